// Round 12
// baseline (229.211 us; speedup 1.0000x reference)
//
#include <hip/hip_runtime.h>
#include <math.h>

static constexpr int NN  = 100000;    // nodes
static constexpr int NE  = 3200000;   // edges
static constexpr int HO  = 1024;      // head out
static constexpr int BSH = 5;         // 32 nodes per bucket
static constexpr int BMASK = 31;
static constexpr int NB  = 3125;      // buckets
static constexpr int NBP = NB + 1;    // loffg row stride
static constexpr int PB  = 256;       // partition blocks
static constexpr int AT  = 512;       // partA threads
static constexpr int CHUNK = NE / PB; // 12500 edges per partition
static constexpr int PER_A = (NB + AT - 1) / AT;  // 7
static constexpr int RPB = 50;        // rows per head block
static constexpr int HB  = NN / RPB;  // 2000 head blocks
static constexpr int CAP = 2048;      // LDS records per bucket (avg 1024, +32 sigma)
static constexpr int BSTRIDE = 1536;  // padded records per bucket in sorted2

typedef float f4v __attribute__((ext_vector_type(4)));

// adjacent buckets -> same XCD (bijective: 5 groups of 391, 3 of 390)
__device__ __forceinline__ int bucket_swz(int blk) {
    int x = blk & 7, g = blk >> 3;
    return (x < 5) ? x * 391 + g : 1955 + (x - 5) * 390 + g;
}

// ---- phase A (fused init): histogram + local bucket-sort into own region ----
__global__ __launch_bounds__(AT) void partA_k(const float* __restrict__ f1,
                                              const float* __restrict__ f2,
                                              const int* __restrict__ src,
                                              const int* __restrict__ dst,
                                              const float* __restrict__ norm,
                                              int* __restrict__ loffg,
                                              uint2* __restrict__ blocked,
                                              float2* __restrict__ x0,
                                              float* __restrict__ xacc,
                                              int* __restrict__ done) {
    __shared__ int hist[NB];
    __shared__ int wt[8];
    int blk = blockIdx.x, t = threadIdx.x;
    int lane = t & 63, w = t >> 6;
    int gi = blk * AT + t;
    if (gi < NN) x0[gi] = make_float2(f1[gi], f2[gi]);
    if (blk == 0) {
        for (int i = t; i < 2 * HO; i += AT) xacc[i] = 0.f;
        if (t == 0) *done = 0;
    }
    for (int i = t; i < NB; i += AT) hist[i] = 0;
    __syncthreads();
    int base = blk * CHUNK;
    for (int i = t; i < CHUNK; i += AT)
        atomicAdd(&hist[dst[base + i] >> BSH], 1);
    __syncthreads();
    int loc[PER_A]; int s = 0;
    int b0 = t * PER_A;
#pragma unroll
    for (int k = 0; k < PER_A; ++k) {
        int i = b0 + k;
        int v = (i < NB) ? hist[i] : 0;
        loc[k] = s; s += v;
    }
    int incl = s;
#pragma unroll
    for (int off = 1; off < 64; off <<= 1) {
        int v = __shfl_up(incl, off, 64);
        if (lane >= off) incl += v;
    }
    if (lane == 63) wt[w] = incl;
    __syncthreads();
    int wpre = 0;
#pragma unroll
    for (int k = 0; k < 8; ++k) if (k < w) wpre += wt[k];
    int carry = wpre + incl - s;
#pragma unroll
    for (int k = 0; k < PER_A; ++k) {
        int i = b0 + k;
        if (i < NB) {
            int e = carry + loc[k];
            loffg[blk * NBP + i] = e;
            hist[i] = e;                 // cursor
        }
    }
    __syncthreads();
    for (int i = t; i < CHUNK; i += AT) {
        int e = base + i;
        int d = dst[e];                  // L2-hot re-read
        int pos = atomicAdd(&hist[d >> BSH], 1);
        blocked[base + pos] = make_uint2((unsigned)src[e] | ((unsigned)(d & BMASK) << 17),
                                         __float_as_uint(norm[e]));
    }
}

// ---- phase B (fused layer 0): per bucket -> padded node-CSR (4B records)
//      + layer-0 aggregation from the LDS copy ----
__global__ __launch_bounds__(256) void sortB_k(const uint2* __restrict__ blocked,
                                               const int* __restrict__ loffg,
                                               unsigned* __restrict__ s2out,
                                               int2* __restrict__ noff,
                                               const float2* __restrict__ x0,
                                               float2* __restrict__ x1,
                                               float2* __restrict__ ssum,
                                               const float* __restrict__ gw,
                                               const float* __restrict__ gb) {
    __shared__ __align__(16) uint2 rec[CAP];      // 16 KB
    __shared__ __align__(16) unsigned ol[CAP];    // 8 KB (node-sorted 4B records)
    __shared__ int wtot[4];
    __shared__ int cnt[32], curs[32], pre4s[32], c4s[32];
    __shared__ float inv[32];
    int t = threadIdx.x;
    int lane = t & 63, w = t >> 6;
    int b = bucket_swz(blockIdx.x);
    int gbase = b * BSTRIDE;
    // strided loffg read: line shared by 16 consecutive buckets on same XCD -> L2 hits
    int o0 = loffg[t * NBP + b];
    int o1 = (b == NB - 1) ? CHUNK : loffg[t * NBP + b + 1];
    int len = o1 - o0;
    if (t < 32) cnt[t] = 0;
    int incl = len;
#pragma unroll
    for (int off = 1; off < 64; off <<= 1) {
        int v = __shfl_up(incl, off, 64);
        if (lane >= off) incl += v;
    }
    if (lane == 63) wtot[w] = incl;
    __syncthreads();
    int wpre = 0, total = 0;
#pragma unroll
    for (int k = 0; k < 4; ++k) {
        int tv = wtot[k];
        if (k < w) wpre += tv;
        total += tv;
    }
    int start = wpre + incl - len;
    if (total > CAP) total = CAP;        // safety clamp (never expected)
    {
        int lm = (len > 0) ? len - 1 : 0;
        int o0c = (o0 < CHUNK - 1) ? o0 : CHUNK - 1;
        const uint2* srcq = blocked + (size_t)t * CHUNK + o0c;
        uint2 q0 = srcq[0];
        uint2 q1 = srcq[lm < 1 ? lm : 1];
        uint2 q2 = srcq[lm < 2 ? lm : 2];
        uint2 q3 = srcq[lm < 3 ? lm : 3];
        uint2 q4 = srcq[lm < 4 ? lm : 4];
        uint2 q5 = srcq[lm < 5 ? lm : 5];
        uint2 q6 = srcq[lm < 6 ? lm : 6];
        uint2 q7 = srcq[lm < 7 ? lm : 7];
        if (len > 0 && start + 0 < CAP) rec[start + 0] = q0;
        if (len > 1 && start + 1 < CAP) rec[start + 1] = q1;
        if (len > 2 && start + 2 < CAP) rec[start + 2] = q2;
        if (len > 3 && start + 3 < CAP) rec[start + 3] = q3;
        if (len > 4 && start + 4 < CAP) rec[start + 4] = q4;
        if (len > 5 && start + 5 < CAP) rec[start + 5] = q5;
        if (len > 6 && start + 6 < CAP) rec[start + 6] = q6;
        if (len > 7 && start + 7 < CAP) rec[start + 7] = q7;
        for (int j = 8; j < len; ++j)
            if (start + j < CAP) rec[start + j] = srcq[j];
    }
    __syncthreads();
    for (int i = t; i < total; i += 256)
        atomicAdd(&cnt[(rec[i].x >> 17) & BMASK], 1);
    __syncthreads();
    if (t < 32) {
        int c = cnt[t];
        int c4 = (c + 3) & ~3;           // pad to x4
        int ic4 = c4;
#pragma unroll
        for (int off = 1; off < 32; off <<= 1) {
            int v = __shfl_up(ic4, off, 32);
            if (t >= off) ic4 += v;
        }
        int pre4 = ic4 - c4;
        curs[t] = pre4;
        pre4s[t] = pre4; c4s[t] = c4;
        inv[t] = 1.0f / fmaxf((float)c, 1.0f);
        noff[(b << BSH) + t] = make_int2(gbase + pre4, gbase + pre4 + c4);
        for (int j = c; j < c4; ++j) {   // zero pads (src=0, w=0 -> contributes 0)
            s2out[gbase + pre4 + j] = 0u;
            ol[pre4 + j] = 0u;
        }
    }
    __syncthreads();
    for (int i = t; i < total; i += 256) {
        uint2 r = rec[i];
        int lo = (r.x >> 17) & BMASK;
        int pos = atomicAdd(&curs[lo], 1);
        float v = __uint_as_float(r.y) * inv[lo];
        int q = (int)(v * 32768.f + 0.5f);
        if (q > 32767) q = 32767;
        unsigned rr = (r.x & 131071u) | ((unsigned)q << 17);
        s2out[gbase + pos] = rr;
        ol[pos] = rr;
    }
    __syncthreads();
    // ---- fused layer 0 for this bucket's 32 nodes (8 lanes/node, no atomics) ----
    {
        int lo = t >> 3, r = t & 7;
        int p0 = pre4s[lo], c4 = c4s[lo];
        float ax = 0.f, ay = 0.f;
        const float qs = 1.0f / 32768.0f;
        for (int i = p0 + 4 * r; i < p0 + c4; i += 32) {
            uint4 q = *reinterpret_cast<const uint4*>(&ol[i]);
            float2 xa = x0[q.x & 131071u]; float wa = (float)(q.x >> 17) * qs;
            float2 xb = x0[q.y & 131071u]; float wb = (float)(q.y >> 17) * qs;
            float2 xc = x0[q.z & 131071u]; float wc = (float)(q.z >> 17) * qs;
            float2 xd = x0[q.w & 131071u]; float wd = (float)(q.w >> 17) * qs;
            ax = fmaf(xa.x, wa, ax); ay = fmaf(xa.y, wa, ay);
            ax = fmaf(xb.x, wb, ax); ay = fmaf(xb.y, wb, ay);
            ax = fmaf(xc.x, wc, ax); ay = fmaf(xc.y, wc, ay);
            ax = fmaf(xd.x, wd, ax); ay = fmaf(xd.y, wd, ay);
        }
#pragma unroll
        for (int off = 1; off < 8; off <<= 1) {
            ax += __shfl_xor(ax, off, 64);
            ay += __shfl_xor(ay, off, 64);
        }
        if (r == 0) {
            int node = (b << BSH) + lo;
            float wv = gw[0], bb = gb[0];
            float2 xv = x0[node];
            float rx = fmaf(xv.x + ax, wv, bb);
            float ry = fmaf(xv.y + ay, wv, bb);
            ssum[node] = make_float2(rx, ry);
            x1[node] = make_float2(fmaxf(rx, 0.f), fmaxf(ry, 0.f));
        }
    }
}

// ---- layers 1,2: 8 lanes/node, one dwordx4 = 4 records per lane ----
__global__ __launch_bounds__(256) void layer_k(const unsigned* __restrict__ s2,
                                               const int2* __restrict__ noff,
                                               const float2* __restrict__ xin,
                                               float2* __restrict__ xout,
                                               float2* __restrict__ ssum,
                                               const float* __restrict__ gw,
                                               const float* __restrict__ gb, int l) {
    int gid = blockIdx.x * 256 + threadIdx.x;
    int node = gid >> 3, r = gid & 7;
    if (node >= NN) return;
    int2 no = noff[node];
    int i0 = no.x, i1 = no.y;            // multiple-of-4 segment, 16B aligned
    float ax = 0.f, ay = 0.f;
    const float qs = 1.0f / 32768.0f;
    for (int i = i0 + 4 * r; i < i1; i += 32) {
        uint4 q = *reinterpret_cast<const uint4*>(s2 + i);
        float2 xa = xin[q.x & 131071u]; float wa = (float)(q.x >> 17) * qs;
        float2 xb = xin[q.y & 131071u]; float wb = (float)(q.y >> 17) * qs;
        float2 xc = xin[q.z & 131071u]; float wc = (float)(q.z >> 17) * qs;
        float2 xd = xin[q.w & 131071u]; float wd = (float)(q.w >> 17) * qs;
        ax = fmaf(xa.x, wa, ax); ay = fmaf(xa.y, wa, ay);
        ax = fmaf(xb.x, wb, ax); ay = fmaf(xb.y, wb, ay);
        ax = fmaf(xc.x, wc, ax); ay = fmaf(xc.y, wc, ay);
        ax = fmaf(xd.x, wd, ax); ay = fmaf(xd.y, wd, ay);
    }
#pragma unroll
    for (int off = 1; off < 8; off <<= 1) {
        ax += __shfl_xor(ax, off, 64);
        ay += __shfl_xor(ay, off, 64);
    }
    if (r == 0) {
        float wv = gw[l], bb = gb[l];
        float2 xv = xin[node];
        float rx = fmaf(xv.x + ax, wv, bb);
        float ry = fmaf(xv.y + ay, wv, bb);
        float2 s = ssum[node];
        ssum[node] = make_float2(s.x + rx, s.y + ry);
        xout[node] = make_float2(fmaxf(rx, 0.f), fmaxf(ry, 0.f));
    }
}

// ---- head: per-block partial of [2,RPB] @ W[RPB,1024] ----
__global__ __launch_bounds__(256) void head_k(const float2* __restrict__ ssum,
                                              const float* __restrict__ W,
                                              float* __restrict__ part) {
    __shared__ float sf0[RPB], sf1[RPB];
    int r0 = blockIdx.x * RPB;
    int t = threadIdx.x;
    const float sc = 1.0f / 3.0f;
    if (t < RPB) {
        float2 s = ssum[r0 + t];
        sf0[t] = s.x * sc;
        sf1[t] = s.y * sc;
    }
    __syncthreads();
    float ax1=0.f, ay1=0.f, az1=0.f, aw1=0.f;
    float ax2=0.f, ay2=0.f, az2=0.f, aw2=0.f;
    int j0 = t * 4;
    const f4v* Wp = reinterpret_cast<const f4v*>(W + (size_t)r0 * HO + j0);
#pragma unroll 5
    for (int k = 0; k < RPB; ++k) {
        f4v w4 = __builtin_nontemporal_load(Wp);
        Wp += HO / 4;
        float v1 = sf0[k], v2 = sf1[k];
        ax1 = fmaf(v1, w4.x, ax1); ay1 = fmaf(v1, w4.y, ay1);
        az1 = fmaf(v1, w4.z, az1); aw1 = fmaf(v1, w4.w, aw1);
        ax2 = fmaf(v2, w4.x, ax2); ay2 = fmaf(v2, w4.y, ay2);
        az2 = fmaf(v2, w4.z, az2); aw2 = fmaf(v2, w4.w, aw2);
    }
    float* pp = part + (size_t)blockIdx.x * 2048;
    pp[j0]   = ax1; pp[j0+1] = ay1; pp[j0+2] = az1; pp[j0+3] = aw1;
    pp[1024+j0]   = ax2; pp[1024+j0+1] = ay2;
    pp[1024+j0+2] = az2; pp[1024+j0+3] = aw2;
}

// ---- reduce partials + last-block final sigmoid ----
__global__ __launch_bounds__(256) void reduce_k(const float* __restrict__ part,
                                                float* __restrict__ xacc,
                                                const float* __restrict__ nb,
                                                float* __restrict__ out,
                                                int* __restrict__ done) {
    int gid = blockIdx.x * 256 + threadIdx.x;   // 0..65535
    int j = gid & 2047;
    int seg = gid >> 11;                        // 0..31
    int b0 = (seg * HB) >> 5, b1 = ((seg + 1) * HB) >> 5;
    float s = 0.f;
    for (int b = b0; b < b1; ++b) s += part[(size_t)b * 2048 + j];
    atomicAdd(&xacc[j], s);
    __threadfence();                            // release xacc updates
    __syncthreads();
    __shared__ int ticket;
    if (threadIdx.x == 0) ticket = atomicAdd(done, 1);
    __syncthreads();
    if (ticket == 255) {                        // last block: all xacc adds visible
        __threadfence();
        int t = threadIdx.x;
        float v = 0.f;
        for (int jj = t; jj < HO; jj += 256)
            v += (xacc[jj] + nb[jj]) * (xacc[HO + jj] + nb[jj]);
        __shared__ float red[256];
        red[t] = v;
        __syncthreads();
        for (int st = 128; st > 0; st >>= 1) {
            if (t < st) red[t] += red[t + st];
            __syncthreads();
        }
        if (t == 0) out[0] = 1.0f / (1.0f + expf(-red[0]));
    }
}

extern "C" void kernel_launch(void* const* d_in, const int* in_sizes, int n_in,
                              void* d_out, int out_size, void* d_ws, size_t ws_size,
                              hipStream_t stream) {
    const float* feat1 = (const float*)d_in[0];
    const float* feat2 = (const float*)d_in[1];
    const float* norm  = (const float*)d_in[2];
    const int*   src   = (const int*)  d_in[3];
    const int*   dst   = (const int*)  d_in[4];
    const float* gin_w = (const float*)d_in[5];
    const float* gin_b = (const float*)d_in[6];
    const float* net_w = (const float*)d_in[7];
    const float* net_b = (const float*)d_in[8];
    float* out = (float*)d_out;

    char* p = (char*)d_ws;
    uint2* blocked   = (uint2*)p;             p += (size_t)NE * 8;            // 25.6 MB
    float* part      = (float*)blocked;       // alias: used only after sortB
    unsigned* sorted2 = (unsigned*)p;         p += (size_t)NB * BSTRIDE * 4;  // 19.2 MB
    int*   loffg     = (int*)p;               p += (size_t)PB * NBP * 4;      // 3.2 MB
    int2*  noff      = (int2*)p;              p += (size_t)NN * 8;            // 0.8 MB
    float2* x0       = (float2*)p;            p += (size_t)NN * 8;
    float2* x1       = (float2*)p;            p += (size_t)NN * 8;
    float2* ssum     = (float2*)p;            p += (size_t)NN * 8;
    float* xacc      = (float*)p;             p += (size_t)2 * HO * 4;
    int*   done      = (int*)p;               p += 16;

    int lg = (NN * 8 + 255) / 256;            // 3125 blocks for layers

    partA_k<<<PB, AT, 0, stream>>>(feat1, feat2, src, dst, norm, loffg, blocked,
                                   x0, xacc, done);
    sortB_k<<<NB, 256, 0, stream>>>(blocked, loffg, sorted2, noff,
                                    x0, x1, ssum, gin_w, gin_b);
    layer_k<<<lg, 256, 0, stream>>>(sorted2, noff, x1, x0, ssum, gin_w, gin_b, 1);
    layer_k<<<lg, 256, 0, stream>>>(sorted2, noff, x0, x1, ssum, gin_w, gin_b, 2);
    head_k<<<HB, 256, 0, stream>>>(ssum, net_w, part);
    reduce_k<<<256, 256, 0, stream>>>(part, xacc, net_b, out, done);
}

// Round 13
// 215.727 us; speedup vs baseline: 1.0625x; 1.0625x over previous
//
#include <hip/hip_runtime.h>
#include <math.h>

static constexpr int NN  = 100000;    // nodes
static constexpr int NE  = 3200000;   // edges
static constexpr int HO  = 1024;      // head out
static constexpr int BSH = 5;         // 32 nodes per bucket
static constexpr int BMASK = 31;
static constexpr int NB  = 3125;      // buckets
static constexpr int NBP = NB + 1;    // loffg row stride
static constexpr int PB  = 256;       // partition blocks
static constexpr int AT  = 1024;      // partA threads (16 waves/CU at 1 block/CU)
static constexpr int CHUNK = NE / PB; // 12500 edges per partition
static constexpr int PER_A = (NB + AT - 1) / AT;  // 4
static constexpr int RPB = 50;        // rows per head block
static constexpr int HB  = NN / RPB;  // 2000 head blocks
static constexpr int CAP = 2048;      // LDS records per bucket (avg 1024, +32 sigma)
static constexpr int BT  = 49;        // bucket tiles for transpose
static constexpr int BSTRIDE = 1536;  // padded records per bucket in sorted2

typedef float f4v __attribute__((ext_vector_type(4)));

// adjacent buckets -> same XCD (bijective: 5 groups of 391, 3 of 390)
__device__ __forceinline__ int bucket_swz(int blk) {
    int x = blk & 7, g = blk >> 3;
    return (x < 5) ? x * 391 + g : 1955 + (x - 5) * 390 + g;
}

// ---- phase A (fused init): histogram + local bucket-sort into own region ----
__global__ __launch_bounds__(AT) void partA_k(const float* __restrict__ f1,
                                              const float* __restrict__ f2,
                                              const int* __restrict__ src,
                                              const int* __restrict__ dst,
                                              const float* __restrict__ norm,
                                              int* __restrict__ loffg,
                                              uint2* __restrict__ blocked,
                                              float2* __restrict__ x0,
                                              float* __restrict__ xacc) {
    __shared__ int hist[NB];
    __shared__ int wt[16];
    int blk = blockIdx.x, t = threadIdx.x;
    int lane = t & 63, w = t >> 6;       // w 0..15
    int gi = blk * AT + t;
    if (gi < NN) x0[gi] = make_float2(f1[gi], f2[gi]);
    if (blk == 0) {
        for (int i = t; i < 2 * HO; i += AT) xacc[i] = 0.f;
    }
    for (int i = t; i < NB; i += AT) hist[i] = 0;
    __syncthreads();
    int base = blk * CHUNK;
    for (int i = t; i < CHUNK; i += AT)
        atomicAdd(&hist[dst[base + i] >> BSH], 1);
    __syncthreads();
    int loc[PER_A]; int s = 0;
    int b0 = t * PER_A;
#pragma unroll
    for (int k = 0; k < PER_A; ++k) {
        int i = b0 + k;
        int v = (i < NB) ? hist[i] : 0;
        loc[k] = s; s += v;
    }
    int incl = s;
#pragma unroll
    for (int off = 1; off < 64; off <<= 1) {
        int v = __shfl_up(incl, off, 64);
        if (lane >= off) incl += v;
    }
    if (lane == 63) wt[w] = incl;
    __syncthreads();
    int wpre = 0;
#pragma unroll
    for (int k = 0; k < 16; ++k) if (k < w) wpre += wt[k];
    int carry = wpre + incl - s;
#pragma unroll
    for (int k = 0; k < PER_A; ++k) {
        int i = b0 + k;
        if (i < NB) {
            int e = carry + loc[k];
            loffg[blk * NBP + i] = e;
            hist[i] = e;                 // cursor
        }
    }
    __syncthreads();
    for (int i = t; i < CHUNK; i += AT) {
        int e = base + i;
        int d = dst[e];                  // L2-hot re-read
        int pos = atomicAdd(&hist[d >> BSH], 1);
        blocked[base + pos] = make_uint2((unsigned)src[e] | ((unsigned)(d & BMASK) << 17),
                                         __float_as_uint(norm[e]));
    }
}

// ---- tiled transpose: loffg[k][b] -> loffT[b][k] (both sides coalesced) ----
__global__ __launch_bounds__(256) void transT_k(const int* __restrict__ loffg,
                                                int* __restrict__ loffT) {
    __shared__ int tile[64][65];
    int bx = blockIdx.x % BT;
    int ky = blockIdx.x / BT;
    int tx = threadIdx.x & 63, ty = threadIdx.x >> 6;
    int b = bx * 64 + tx;
#pragma unroll
    for (int j = 0; j < 16; ++j) {
        int k = ky * 64 + ty + j * 4;
        tile[ty + j * 4][tx] = (b < NB) ? loffg[k * NBP + b] : 0;
    }
    __syncthreads();
#pragma unroll
    for (int j = 0; j < 16; ++j) {
        int row = ty + j * 4;
        int bb = bx * 64 + row;
        if (bb < NB) loffT[(size_t)bb * PB + ky * 64 + tx] = tile[tx][row];
    }
}

// ---- phase B: per bucket -> padded node-CSR with 4B quantized records ----
// record = src(17b) | q15(w/deg)<<17 ; node segments padded to x4 (zero recs)
__global__ __launch_bounds__(256) void sortB_k(const uint2* __restrict__ blocked,
                                               const int* __restrict__ loffT,
                                               unsigned* __restrict__ s2out,
                                               int2* __restrict__ noff) {
    __shared__ uint2 rec[CAP];
    __shared__ int wtot[4];
    __shared__ int cnt[32], curs[32];
    __shared__ float inv[32];
    int t = threadIdx.x;
    int lane = t & 63, w = t >> 6;
    int b = bucket_swz(blockIdx.x);
    int gbase = b * BSTRIDE;
    int o0 = loffT[(size_t)b * PB + t];
    int o1 = (b == NB - 1) ? CHUNK : loffT[(size_t)(b + 1) * PB + t];
    int len = o1 - o0;
    if (t < 32) cnt[t] = 0;
    int incl = len;
#pragma unroll
    for (int off = 1; off < 64; off <<= 1) {
        int v = __shfl_up(incl, off, 64);
        if (lane >= off) incl += v;
    }
    if (lane == 63) wtot[w] = incl;
    __syncthreads();
    int wpre = 0, total = 0;
#pragma unroll
    for (int k = 0; k < 4; ++k) {
        int tv = wtot[k];
        if (k < w) wpre += tv;
        total += tv;
    }
    int start = wpre + incl - len;
    if (total > CAP) total = CAP;        // safety clamp (never expected)
    {
        int lm = (len > 0) ? len - 1 : 0;
        int o0c = (o0 < CHUNK - 1) ? o0 : CHUNK - 1;
        const uint2* srcq = blocked + (size_t)t * CHUNK + o0c;
        uint2 q0 = srcq[0];
        uint2 q1 = srcq[lm < 1 ? lm : 1];
        uint2 q2 = srcq[lm < 2 ? lm : 2];
        uint2 q3 = srcq[lm < 3 ? lm : 3];
        uint2 q4 = srcq[lm < 4 ? lm : 4];
        uint2 q5 = srcq[lm < 5 ? lm : 5];
        uint2 q6 = srcq[lm < 6 ? lm : 6];
        uint2 q7 = srcq[lm < 7 ? lm : 7];
        if (len > 0 && start + 0 < CAP) rec[start + 0] = q0;
        if (len > 1 && start + 1 < CAP) rec[start + 1] = q1;
        if (len > 2 && start + 2 < CAP) rec[start + 2] = q2;
        if (len > 3 && start + 3 < CAP) rec[start + 3] = q3;
        if (len > 4 && start + 4 < CAP) rec[start + 4] = q4;
        if (len > 5 && start + 5 < CAP) rec[start + 5] = q5;
        if (len > 6 && start + 6 < CAP) rec[start + 6] = q6;
        if (len > 7 && start + 7 < CAP) rec[start + 7] = q7;
        for (int j = 8; j < len; ++j)
            if (start + j < CAP) rec[start + j] = srcq[j];
    }
    __syncthreads();
    for (int i = t; i < total; i += 256)
        atomicAdd(&cnt[(rec[i].x >> 17) & BMASK], 1);
    __syncthreads();
    if (t < 32) {
        int c = cnt[t];
        int c4 = (c + 3) & ~3;           // padded to x4
        int ic4 = c4;
#pragma unroll
        for (int off = 1; off < 32; off <<= 1) {
            int v = __shfl_up(ic4, off, 32);
            if (t >= off) ic4 += v;
        }
        int pre4 = ic4 - c4;
        curs[t] = pre4;
        inv[t] = 1.0f / fmaxf((float)c, 1.0f);
        noff[(b << BSH) + t] = make_int2(gbase + pre4, gbase + pre4 + c4);
        for (int j = c; j < c4; ++j) s2out[gbase + pre4 + j] = 0u;  // zero pads
    }
    __syncthreads();
    for (int i = t; i < total; i += 256) {
        uint2 r = rec[i];
        int lo = (r.x >> 17) & BMASK;
        int pos = atomicAdd(&curs[lo], 1);
        float v = __uint_as_float(r.y) * inv[lo];
        int q = (int)(v * 32768.f + 0.5f);
        if (q > 32767) q = 32767;
        s2out[gbase + pos] = (r.x & 131071u) | ((unsigned)q << 17);
    }
}

// ---- per-layer: 8 lanes/node, one dwordx4 = 4 records per lane ----
template<int L0>
__global__ __launch_bounds__(256) void layer_k(const unsigned* __restrict__ s2,
                                               const int2* __restrict__ noff,
                                               const float2* __restrict__ xin,
                                               float2* __restrict__ xout,
                                               float2* __restrict__ ssum,
                                               const float* __restrict__ gw,
                                               const float* __restrict__ gb, int l) {
    int gid = blockIdx.x * 256 + threadIdx.x;
    int node = gid >> 3, r = gid & 7;
    if (node >= NN) return;
    int2 no = noff[node];
    int i0 = no.x, i1 = no.y;            // multiple-of-4 segment, 16B aligned
    float ax = 0.f, ay = 0.f;
    const float qs = 1.0f / 32768.0f;
    for (int i = i0 + 4 * r; i < i1; i += 32) {
        uint4 q = *reinterpret_cast<const uint4*>(s2 + i);
        float2 xa = xin[q.x & 131071u]; float wa = (float)(q.x >> 17) * qs;
        float2 xb = xin[q.y & 131071u]; float wb = (float)(q.y >> 17) * qs;
        float2 xc = xin[q.z & 131071u]; float wc = (float)(q.z >> 17) * qs;
        float2 xd = xin[q.w & 131071u]; float wd = (float)(q.w >> 17) * qs;
        ax = fmaf(xa.x, wa, ax); ay = fmaf(xa.y, wa, ay);
        ax = fmaf(xb.x, wb, ax); ay = fmaf(xb.y, wb, ay);
        ax = fmaf(xc.x, wc, ax); ay = fmaf(xc.y, wc, ay);
        ax = fmaf(xd.x, wd, ax); ay = fmaf(xd.y, wd, ay);
    }
#pragma unroll
    for (int off = 1; off < 8; off <<= 1) {
        ax += __shfl_xor(ax, off, 64);
        ay += __shfl_xor(ay, off, 64);
    }
    if (r == 0) {
        float wv = gw[l], bb = gb[l];
        float2 xv = xin[node];
        float rx = fmaf(xv.x + ax, wv, bb);
        float ry = fmaf(xv.y + ay, wv, bb);
        if (L0) ssum[node] = make_float2(rx, ry);
        else { float2 s = ssum[node]; ssum[node] = make_float2(s.x + rx, s.y + ry); }
        xout[node] = make_float2(fmaxf(rx, 0.f), fmaxf(ry, 0.f));
    }
}

// ---- head: per-block partial of [2,RPB] @ W[RPB,1024] ----
__global__ __launch_bounds__(256) void head_k(const float2* __restrict__ ssum,
                                              const float* __restrict__ W,
                                              float* __restrict__ part) {
    __shared__ float sf0[RPB], sf1[RPB];
    int r0 = blockIdx.x * RPB;
    int t = threadIdx.x;
    const float sc = 1.0f / 3.0f;
    if (t < RPB) {
        float2 s = ssum[r0 + t];
        sf0[t] = s.x * sc;
        sf1[t] = s.y * sc;
    }
    __syncthreads();
    float ax1=0.f, ay1=0.f, az1=0.f, aw1=0.f;
    float ax2=0.f, ay2=0.f, az2=0.f, aw2=0.f;
    int j0 = t * 4;
    const f4v* Wp = reinterpret_cast<const f4v*>(W + (size_t)r0 * HO + j0);
#pragma unroll 5
    for (int k = 0; k < RPB; ++k) {
        f4v w4 = __builtin_nontemporal_load(Wp);
        Wp += HO / 4;
        float v1 = sf0[k], v2 = sf1[k];
        ax1 = fmaf(v1, w4.x, ax1); ay1 = fmaf(v1, w4.y, ay1);
        az1 = fmaf(v1, w4.z, az1); aw1 = fmaf(v1, w4.w, aw1);
        ax2 = fmaf(v2, w4.x, ax2); ay2 = fmaf(v2, w4.y, ay2);
        az2 = fmaf(v2, w4.z, az2); aw2 = fmaf(v2, w4.w, aw2);
    }
    float* pp = part + (size_t)blockIdx.x * 2048;
    pp[j0]   = ax1; pp[j0+1] = ay1; pp[j0+2] = az1; pp[j0+3] = aw1;
    pp[1024+j0]   = ax2; pp[1024+j0+1] = ay2;
    pp[1024+j0+2] = az2; pp[1024+j0+3] = aw2;
}

// ---- reduce partials (256 blocks, 32-way row split, atomics into xacc) ----
__global__ __launch_bounds__(256) void reduce_k(const float* __restrict__ part,
                                                float* __restrict__ xacc) {
    int gid = blockIdx.x * 256 + threadIdx.x;   // 0..65535
    int j = gid & 2047;
    int seg = gid >> 11;                        // 0..31
    int b0 = (seg * HB) >> 5, b1 = ((seg + 1) * HB) >> 5;
    float s = 0.f;
    for (int b = b0; b < b1; ++b) s += part[(size_t)b * 2048 + j];
    atomicAdd(&xacc[j], s);
}

// ---- final: sigmoid(sum_j (x1+b)(x2+b)) ----
__global__ void final_k(const float* __restrict__ xacc, const float* __restrict__ nb,
                        float* __restrict__ out) {
    __shared__ float red[256];
    int t = threadIdx.x;
    float v = 0.f;
    for (int j = t; j < HO; j += 256)
        v += (xacc[j] + nb[j]) * (xacc[HO + j] + nb[j]);
    red[t] = v;
    __syncthreads();
    for (int s = 128; s > 0; s >>= 1) {
        if (t < s) red[t] += red[t + s];
        __syncthreads();
    }
    if (t == 0) out[0] = 1.0f / (1.0f + expf(-red[0]));
}

extern "C" void kernel_launch(void* const* d_in, const int* in_sizes, int n_in,
                              void* d_out, int out_size, void* d_ws, size_t ws_size,
                              hipStream_t stream) {
    const float* feat1 = (const float*)d_in[0];
    const float* feat2 = (const float*)d_in[1];
    const float* norm  = (const float*)d_in[2];
    const int*   src   = (const int*)  d_in[3];
    const int*   dst   = (const int*)  d_in[4];
    const float* gin_w = (const float*)d_in[5];
    const float* gin_b = (const float*)d_in[6];
    const float* net_w = (const float*)d_in[7];
    const float* net_b = (const float*)d_in[8];
    float* out = (float*)d_out;

    char* p = (char*)d_ws;
    uint2* blocked   = (uint2*)p;             p += (size_t)NE * 8;            // 25.6 MB
    float* part      = (float*)blocked;       // alias: used only after sortB
    unsigned* sorted2 = (unsigned*)p;         p += (size_t)NB * BSTRIDE * 4;  // 19.2 MB
    int*   loffg     = (int*)p;               p += (size_t)PB * NBP * 4;      // 3.2 MB
    int*   loffT     = (int*)p;               p += (size_t)NB * PB * 4;       // 3.2 MB
    int2*  noff      = (int2*)p;              p += (size_t)NN * 8;            // 0.8 MB
    float2* x0       = (float2*)p;            p += (size_t)NN * 8;
    float2* x1       = (float2*)p;            p += (size_t)NN * 8;
    float2* ssum     = (float2*)p;            p += (size_t)NN * 8;
    float* xacc      = (float*)p;             p += (size_t)2 * HO * 4;

    int lg = (NN * 8 + 255) / 256;            // 3125 blocks for layers

    partA_k<<<PB, AT, 0, stream>>>(feat1, feat2, src, dst, norm, loffg, blocked,
                                   x0, xacc);
    transT_k<<<BT * 4, 256, 0, stream>>>(loffg, loffT);
    sortB_k<<<NB, 256, 0, stream>>>(blocked, loffT, sorted2, noff);

    layer_k<1><<<lg, 256, 0, stream>>>(sorted2, noff, x0, x1, ssum, gin_w, gin_b, 0);
    layer_k<0><<<lg, 256, 0, stream>>>(sorted2, noff, x1, x0, ssum, gin_w, gin_b, 1);
    layer_k<0><<<lg, 256, 0, stream>>>(sorted2, noff, x0, x1, ssum, gin_w, gin_b, 2);

    head_k<<<HB, 256, 0, stream>>>(ssum, net_w, part);
    reduce_k<<<256, 256, 0, stream>>>(part, xacc);
    final_k<<<1, 256, 0, stream>>>(xacc, net_b, out);
}